// Round 22
// baseline (113.126 us; speedup 1.0000x reference)
//
#include <hip/hip_runtime.h>
#include <hip/hip_bf16.h>
#include <math.h>

#define NB 32
#define NS 1024
#define NH 512
#define NE 1024   // 2H
#define NEGV -1e10f

typedef _Float16 f16x8 __attribute__((ext_vector_type(8)));
typedef _Float16 f16x4 __attribute__((ext_vector_type(4)));
typedef float f32x4 __attribute__((ext_vector_type(4)));

__device__ __forceinline__ float fast_tanh(float x) {
  float t = __expf(2.f * x);
  return (t - 1.f) * __builtin_amdgcn_rcpf(t + 1.f);
}

// c[b][h] = b_attn[h] + sum_e hidden[b][e] * W_h[e][h]   (fp32, tiny)
__global__ __launch_bounds__(256) void proj_h_kernel(
    const float* __restrict__ hidden, const float* __restrict__ W_attn,
    const float* __restrict__ b_attn, float* __restrict__ c) {
  int b = blockIdx.x >> 1;
  int h = ((blockIdx.x & 1) << 8) + threadIdx.x;
  __shared__ float hid[NH];
  for (int e = threadIdx.x; e < NH; e += 256) hid[e] = hidden[b * NH + e];
  __syncthreads();
  float acc = b_attn[h];
#pragma unroll 8
  for (int e = 0; e < NH; ++e) acc = fmaf(hid[e], W_attn[(size_t)e * NH + h], acc);
  c[b * NH + h] = acc;
}

// Pack W_e into MFMA B-fragment order. BYTE layout (R14-verified):
//   (ks*8 + wslice)*4096 + nj*1024 + lane*16  <-  halfs j=0..7 of
//   W_e[ks*32 + (lane>>4)*8 + j][wslice*64 + nj*16 + (lane&15)]
__global__ __launch_bounds__(256) void prep_We_kernel(
    const float* __restrict__ W_attn, _Float16* __restrict__ Bp) {
  int ks = blockIdx.x;  // 0..31
  int t = threadIdx.x;
#pragma unroll
  for (int p = 0; p < 8; ++p) {
    int f = (p << 8) + t;        // 0..2047
    int ws = f >> 8;             // 0..7  (64-col slice)
    int nj = (f >> 6) & 3;       // 0..3
    int lane = f & 63;
    int col = (ws << 6) + (nj << 4) + (lane & 15);
    int kb = (ks << 5) + ((lane >> 4) << 3);
    f16x8 h;
#pragma unroll
    for (int j = 0; j < 8; ++j)
      h[j] = (_Float16)W_attn[(size_t)(NH + kb + j) * NH + col];
    *(f16x8*)((char*)Bp + (size_t)(((ks << 3) + ws) << 12) + (nj << 10) + (lane << 4)) = h;
  }
}

// Fused  tanh(enc@W_e + c) . W_v  partials.
// R20 body shrunk to 2-blocks/CU residency (the one untried combination:
// clean structure AND occupancy):
//   BM=32, BN=512, 512 thr / 8 waves (wave 32x64, acc 2x4 = 32 AGPR).
//   Phase 1: whole 32x1024 A-panel staged once — contiguous 4 KB-row reads,
//     cvt fp16, swizzled 64 KB LDS. ONE barrier.
//   Phase 2: barrier-free K-loop — 2 ds_read_b128 af + packed-Bp register
//     stream (depth-1 bfE/bfO). With no compute-phase barriers, the 2
//     resident blocks' stage and compute phases overlap freely (TLP).
__global__ __launch_bounds__(512) void score_kernel(
    const float* __restrict__ enc, const _Float16* __restrict__ Bp,
    const float* __restrict__ c, const float* __restrict__ Wv,
    float* __restrict__ spart) {
  __shared__ _Float16 Afp16[32 * 1024];  // 64 KB, row stride 2048 B, swizzled
  const int tid = threadIdx.x;
  const int lane = tid & 63;
  const int wid = tid >> 6;        // 0..7 = wave's 64-col slice
  const int r15 = lane & 15;
  const int id = blockIdx.x;                  // 0..1023
  const int mt = ((id & 7) << 7) + (id >> 3); // bijective XCD swizzle (1024%8==0)
  const int b = mt >> 5;
  const int s0 = (mt & 31) << 5;
  const float* encb = enc + ((size_t)b * NS + s0) * NE;
  const char* Bbase = (const char*)Bp + ((size_t)wid << 12);  // this slice's stream

  // ---- Phase 1: stage 32x1024 A-panel, fully contiguous reads ----
  // pass p: float4 index f = p*512+tid; row = f>>8 (256 float4/row), kq = f&255.
  // LDS byte = row*2048 + kq*8, XOR (row&7)<<4 (2-way alias rows r/r+8 = free).
#pragma unroll 4
  for (int p = 0; p < 16; ++p) {
    int f = (p << 9) + tid;
    int row = f >> 8;
    int kq = f & 255;
    float4 v = *(const float4*)(encb + ((size_t)row << 10) + (kq << 2));
    f16x4 h;
    h[0] = (_Float16)v.x; h[1] = (_Float16)v.y;
    h[2] = (_Float16)v.z; h[3] = (_Float16)v.w;
    int off = (row << 11) + (kq << 3);
    off ^= (row & 7) << 4;
    *(f16x4*)((char*)Afp16 + off) = h;
  }
  __syncthreads();  // the only barrier

  f32x4 acc[2][4];
#pragma unroll
  for (int i = 0; i < 2; ++i)
#pragma unroll
    for (int j = 0; j < 4; ++j) acc[i][j] = (f32x4)0.f;

  // B fragments for k-slice KS (0..31): 4 contiguous dwordx4 per lane.
#define BLOAD(ARR, KS)                                                           \
  _Pragma("unroll") for (int nj = 0; nj < 4; ++nj)                               \
      ARR[nj] = *(const f16x8*)(Bbase + ((size_t)(KS) << 15) +                   \
                                (nj << 10) + (lane << 4));

  // One k-slice (8 MFMA): af[mi] = one ds_read_b128 at
  // row=(mi*16)+r15 (0..31), byte = row*2048 + KS*64 + (lane>>4)*16, XOR (row&7)<<4.
#define COMPUTE(KS, ARR)                                                         \
  {                                                                              \
    f16x8 af[2];                                                                 \
    _Pragma("unroll") for (int mi = 0; mi < 2; ++mi) {                           \
      int row = (mi << 4) + r15;                                                 \
      int off = (row << 11) + ((KS) << 6) + ((lane >> 4) << 4);                  \
      off ^= (row & 7) << 4;                                                     \
      af[mi] = *(const f16x8*)((const char*)Afp16 + off);                        \
    }                                                                            \
    _Pragma("unroll") for (int mi = 0; mi < 2; ++mi)                             \
      _Pragma("unroll") for (int nj = 0; nj < 4; ++nj)                           \
        acc[mi][nj] = __builtin_amdgcn_mfma_f32_16x16x32_f16(af[mi], ARR[nj],    \
                                                             acc[mi][nj], 0, 0, 0); \
  }

  // ---- Phase 2: barrier-free K-loop, static bf rotation (rule #20) ----
  f16x8 bfE[4], bfO[4];
  BLOAD(bfE, 0);
  for (int ks = 0; ks < 32; ks += 2) {
    BLOAD(bfO, ks + 1);
    COMPUTE(ks, bfE);
    if (ks < 30) BLOAD(bfE, ks + 2);
    COMPUTE(ks + 1, bfO);
  }
#undef BLOAD
#undef COMPUTE

  // ---- epilogue: fast-tanh + W_v dot over this wave's 64 cols ----
  float sr[2][4];
#pragma unroll
  for (int i = 0; i < 2; ++i)
#pragma unroll
    for (int r = 0; r < 4; ++r) sr[i][r] = 0.f;
#pragma unroll
  for (int nj = 0; nj < 4; ++nj) {
    int hcol = (wid << 6) + (nj << 4) + r15;
    float wvj = Wv[hcol];
    float cvj = c[b * NH + hcol];
#pragma unroll
    for (int mi = 0; mi < 2; ++mi)
#pragma unroll
      for (int r = 0; r < 4; ++r)
        sr[mi][r] += wvj * fast_tanh(acc[mi][nj][r] + cvj);
  }
  // reduce across the 16 col-lanes (fixed order -> deterministic)
#pragma unroll
  for (int off = 1; off < 16; off <<= 1)
#pragma unroll
    for (int mi = 0; mi < 2; ++mi)
#pragma unroll
      for (int r = 0; r < 4; ++r) sr[mi][r] += __shfl_xor(sr[mi][r], off, 64);
  if (r15 == 0) {
    float* dst = spart + (size_t)wid * NB * NS + b * NS + s0;
#pragma unroll
    for (int mi = 0; mi < 2; ++mi)
#pragma unroll
      for (int r = 0; r < 4; ++r)
        dst[(mi << 4) + ((lane >> 4) << 2) + r] = sr[mi][r];
  }
}

// masked softmax over S per batch row; sums the 8 score partials first
__global__ __launch_bounds__(256) void softmax_kernel(
    const float* __restrict__ spart, const int* __restrict__ mask,
    float* __restrict__ attn) {
  int b = blockIdx.x, tid = threadIdx.x;
  __shared__ float red[8];
  float v[4];
  float mx = -INFINITY;
#pragma unroll
  for (int j = 0; j < 4; ++j) {
    int s = tid + (j << 8);
    float x = 0.f;
#pragma unroll
    for (int p = 0; p < 8; ++p) x += spart[(size_t)p * NB * NS + b * NS + s];
    v[j] = (mask[b * NS + s] == 0) ? NEGV : x;
    mx = fmaxf(mx, v[j]);
  }
#pragma unroll
  for (int off = 32; off >= 1; off >>= 1) mx = fmaxf(mx, __shfl_xor(mx, off, 64));
  if ((tid & 63) == 0) red[tid >> 6] = mx;
  __syncthreads();
  mx = fmaxf(fmaxf(red[0], red[1]), fmaxf(red[2], red[3]));
  float sum = 0.f;
#pragma unroll
  for (int j = 0; j < 4; ++j) {
    v[j] = __expf(v[j] - mx);
    sum += v[j];
  }
#pragma unroll
  for (int off = 32; off >= 1; off >>= 1) sum += __shfl_xor(sum, off, 64);
  __syncthreads();
  if ((tid & 63) == 0) red[4 + (tid >> 6)] = sum;
  __syncthreads();
  float inv = 1.f / (red[4] + red[5] + red[6] + red[7]);
#pragma unroll
  for (int j = 0; j < 4; ++j) attn[b * NS + tid + (j << 8)] = v[j] * inv;
}

// partial context over a 64-row S chunk (fp32 enc)
__global__ __launch_bounds__(256) void ctx_partial_kernel(
    const float* __restrict__ enc, const float* __restrict__ attn,
    float* __restrict__ partial) {
  int ch = blockIdx.x;  // 0..15
  int b = blockIdx.y;
  int tid = threadIdx.x;
  __shared__ float w[64];
  if (tid < 64) w[tid] = attn[b * NS + (ch << 6) + tid];
  __syncthreads();
  const float* encb = enc + ((size_t)b * NS + (ch << 6)) * NE;
  float4 acc = make_float4(0.f, 0.f, 0.f, 0.f);
  int e = tid << 2;
  for (int s = 0; s < 64; ++s) {
    float4 x = *(const float4*)(encb + (size_t)s * NE + e);
    float ws_ = w[s];
    acc.x = fmaf(ws_, x.x, acc.x);
    acc.y = fmaf(ws_, x.y, acc.y);
    acc.z = fmaf(ws_, x.z, acc.z);
    acc.w = fmaf(ws_, x.w, acc.w);
  }
  *(float4*)(partial + ((size_t)(b * 16 + ch)) * NE + e) = acc;
}

__global__ __launch_bounds__(256) void ctx_reduce_kernel(
    const float* __restrict__ partial, float* __restrict__ ctx) {
  int b = blockIdx.x;
  int e = threadIdx.x << 2;
  float4 acc = make_float4(0.f, 0.f, 0.f, 0.f);
  for (int ch = 0; ch < 16; ++ch) {
    float4 x = *(const float4*)(partial + ((size_t)(b * 16 + ch)) * NE + e);
    acc.x += x.x;
    acc.y += x.y;
    acc.z += x.z;
    acc.w += x.w;
  }
  *(float4*)(ctx + (size_t)b * NE + e) = acc;
}

extern "C" void kernel_launch(void* const* d_in, const int* in_sizes, int n_in,
                              void* d_out, int out_size, void* d_ws, size_t ws_size,
                              hipStream_t stream) {
  const float* hidden = (const float*)d_in[0];
  const float* enc = (const float*)d_in[1];
  const int* mask = (const int*)d_in[2];
  const float* W_attn = (const float*)d_in[3];
  const float* b_attn = (const float*)d_in[4];
  const float* W_v = (const float*)d_in[5];

  float* ctx = (float*)d_out;   // context: 32*1024
  float* attn = ctx + NB * NS;  // attn_w: 32*1024

  char* ws = (char*)d_ws;
  float* c = (float*)ws;                             // 64 KB
  float* spart = (float*)(ws + 65536);               // 8*32*1024 f32 = 1 MB
  float* partial = (float*)(ws + 65536 + 1048576);   // 32*16*1024 f32 = 2 MB
  _Float16* Bp = (_Float16*)(ws + 65536 + 1048576 + 2097152);  // 1 MB packed

  proj_h_kernel<<<64, 256, 0, stream>>>(hidden, W_attn, b_attn, c);
  prep_We_kernel<<<32, 256, 0, stream>>>(W_attn, Bp);
  score_kernel<<<1024, 512, 0, stream>>>(enc, Bp, c, W_v, spart);
  softmax_kernel<<<NB, 256, 0, stream>>>(spart, mask, attn);
  ctx_partial_kernel<<<dim3(16, NB), 256, 0, stream>>>(enc, attn, partial);
  ctx_reduce_kernel<<<NB, 256, 0, stream>>>(partial, ctx);
}